// Round 12
// baseline (481.754 us; speedup 1.0000x reference)
//
#include <hip/hip_runtime.h>
#include <stdint.h>

typedef unsigned long long ull;
typedef unsigned int u32;
typedef __attribute__((ext_vector_type(8))) short bf16x8;
typedef __attribute__((ext_vector_type(4))) float f32x4;

// sizes: b=64, f=4, v=256, d=16384, ITERS=10; d-words = 256
//
// ws layout (bytes):
//   in_bits [64][256] ull        @ 0         (131072)
//   est0    [64][4][256] ull     @ 131072    (524288)
//   est1    [64][4][256] ull     @ 655360    (524288)
//   cbw     [4][256][256] ull    @ 1179648   (2097152)  [f][w][v]: bit l = sign cb[f][v][w*64+l]
//   cbT     [4][4][16384] ull    @ 3276800   (2097152)  [f][j][d]: bit l = sign cb[f][j*64+l][d]
//   simAB   [4][16384] u32       @ 5373952   (262144)   mode0: frag-order (sh|sl<<16); mode1: linear q16
//   bar     [64] ull             @ 5636096   (512)      8 barrier counters, 64B apart (bar[c*8])
//
// bit = 1 <=> value == -1; product of bipolars = XOR.
// signed split: sim = 16384-2h = 256*sh + sl (sh in [-64,64], sl in [0,255], both bf16-exact)
// est bit = ( sum_v sim[v]*cb[v,d] < 0 )
// Cross-XCD data (est*, simAB, bar) via AGENT-scope relaxed atomics (proven r9/r10: absmax 0).
// Barrier: per-XCD-group counters (32 blocks each), monotonic target 32*ph, 8 pollers/block.

#define AS __HIP_MEMORY_SCOPE_AGENT
__device__ __forceinline__ ull ald(const ull* p) {
    return __hip_atomic_load(p, __ATOMIC_RELAXED, AS);
}
__device__ __forceinline__ void ast(ull* p, ull v) {
    __hip_atomic_store(p, v, __ATOMIC_RELAXED, AS);
}
__device__ __forceinline__ void ast32(u32* p, u32 v) {
    __hip_atomic_store(p, v, __ATOMIC_RELAXED, AS);
}

// ---- setup: pack input + init_estimates + codebook in ONE dispatch, 16 words/wave ----
__global__ __launch_bounds__(1024) void pack_mega(
        const float* __restrict__ in, const float* __restrict__ est_f,
        const float* __restrict__ cb,
        ull* __restrict__ in_bits, ull* __restrict__ est_bits, ull* __restrict__ cbw,
        ull* __restrict__ bar) {
    if (blockIdx.x == 0 && threadIdx.x < 64) bar[threadIdx.x] = 0;  // re-zero counters every launch
    int wid  = (int)((blockIdx.x * 1024 + threadIdx.x) >> 6);   // 21504 waves
    int lane = threadIdx.x & 63;
    int w0 = wid * 16;
    const float* s;
    int wloc;
    if (w0 < 16384)      { s = in;    wloc = w0; }
    else if (w0 < 81920) { s = est_f; wloc = w0 - 16384; }
    else                 { s = cb;    wloc = w0 - 81920; }
    ull ball[16];
    #pragma unroll
    for (int k = 0; k < 16; ++k) {
        float x = s[(size_t)(wloc + k) * 64 + lane];
        ball[k] = __ballot(x < 0.0f);
    }
    if (lane == 0) {
        if (w0 < 16384) {
            #pragma unroll
            for (int k = 0; k < 16; ++k) in_bits[wloc + k] = ball[k];
        } else if (w0 < 81920) {
            #pragma unroll
            for (int k = 0; k < 16; ++k) est_bits[wloc + k] = ball[k];
        } else {
            #pragma unroll
            for (int k = 0; k < 16; ++k) {
                int g = wloc + k;             // (f*256+v)*256 + w
                int f = g >> 16, v = (g >> 8) & 255, w = g & 255;
                cbw[(size_t)(f * 256 + w) * 256 + v] = ball[k];
            }
        }
    }
}

__global__ __launch_bounds__(1024) void pack_cbT(const ull* __restrict__ cbw, ull* __restrict__ cbT) {
    int wid  = (int)((blockIdx.x * 1024 + threadIdx.x) >> 6);   // 16384 waves
    int lane = threadIdx.x & 63;
    int f = wid >> 12, j = (wid >> 10) & 3, w = (wid >> 2) & 255, s2 = wid & 3;
    ull cw = cbw[(size_t)(f * 256 + w) * 256 + j * 64 + lane];
    ull ball[16];
    #pragma unroll
    for (int k = 0; k < 16; ++k)
        ball[k] = __ballot((cw >> (s2 * 16 + k)) & 1ull);
    if (lane == 0) {
        #pragma unroll
        for (int k = 0; k < 16; ++k)
            cbT[(size_t)(f * 4 + j) * 16384 + w * 64 + s2 * 16 + k] = ball[k];
    }
}

// ONE persistent kernel, 256 blocks x 1024 threads (16 waves), ~18KB LDS.
// Codebook words live in VGPRs (phase A) / LDS s_bT (phase B) for the whole kernel.
__global__ __launch_bounds__(1024, 4) void reso_kernel(
        const ull* __restrict__ in_bits, ull* __restrict__ est0, ull* __restrict__ est1,
        const ull* __restrict__ cbw, const ull* __restrict__ cbT,
        u32* __restrict__ simAB, ull* __restrict__ bar, float* __restrict__ out) {
    __shared__ short s_p[4][16][64];              // 8KB [bi][wave][v-local]
    __shared__ ull s_bT[1024];                    // 8KB [j][256 d-local]
    __shared__ ull s_ball[64][4];                 // 2KB [wave*4+ntl][r]

    int t = threadIdx.x, lane = t & 63, wave = t >> 6;
    int bid = blockIdx.x;
    int f    = (bid & 7) >> 1;                    // XCD-swizzled: each XCD owns one f
    int sub  = (bid & 1) * 32 + (bid >> 3);       // 0..63
    int vblk = sub & 3, bblk = sub >> 2;          // A-role
    int dblk = sub;                               // B-role

    // ---- prologue: codebook words -> VGPRs (held forever), cbT bits -> LDS ----
    ull cw[16];
    {
        const ull* cbase = cbw + (size_t)(f * 256 + wave * 16) * 256 + vblk * 64 + lane;
        #pragma unroll
        for (int k = 0; k < 16; ++k) cw[k] = cbase[(size_t)k * 256];
    }
    s_bT[t] = cbT[((size_t)f * 4 + (t >> 8)) * 16384 + dblk * 256 + (t & 255)];

    // A-role per-lane constants
    const int bA = bblk * 4 + (lane >> 4);
    const int wA = wave * 16 + (lane & 15);
    const ull inb = in_bits[(size_t)bA * 256 + wA];
    __syncthreads();

    int ph = 0;
    for (int itr = 0; itr <= 10; ++itr) {
        ull* estIn  = (itr & 1) ? est1 : est0;
        ull* estOut = (itr & 1) ? est0 : est1;
        const bool mode1 = (itr == 10);

        // ================= phase A: popcount sim (all in registers) =================
        {
            ull e0 = ald(&estIn[(size_t)(bA * 4 + 0) * 256 + wA]);
            ull e1 = ald(&estIn[(size_t)(bA * 4 + 1) * 256 + wA]);
            ull e2 = ald(&estIn[(size_t)(bA * 4 + 2) * 256 + wA]);
            ull e3 = ald(&estIn[(size_t)(bA * 4 + 3) * 256 + wA]);
            ull ef = (f == 0) ? e0 : ((f == 1) ? e1 : ((f == 2) ? e2 : e3));
            ull ne = mode1 ? ef : (inb ^ e0 ^ e1 ^ e2 ^ e3 ^ ef);
            u32 ne_lo = (u32)ne, ne_hi = (u32)(ne >> 32);

            int acc0 = 0, acc1 = 0, acc2 = 0, acc3 = 0;
            #pragma unroll
            for (int k = 0; k < 16; ++k) {
                u32 cl = (u32)cw[k], ch = (u32)(cw[k] >> 32);
                #pragma unroll
                for (int bi = 0; bi < 4; ++bi) {
                    u32 a0 = __builtin_amdgcn_readlane(ne_lo, bi * 16 + k);
                    u32 a1 = __builtin_amdgcn_readlane(ne_hi, bi * 16 + k);
                    int p = __builtin_popcount(cl ^ a0) + __builtin_popcount(ch ^ a1);
                    if (bi == 0) acc0 += p; else if (bi == 1) acc1 += p;
                    else if (bi == 2) acc2 += p; else acc3 += p;
                }
            }
            s_p[0][wave][lane] = (short)acc0;
            s_p[1][wave][lane] = (short)acc1;
            s_p[2][wave][lane] = (short)acc2;
            s_p[3][wave][lane] = (short)acc3;
        }
        __syncthreads();
        if (t < 256) {
            int bi = t >> 6, v2 = t & 63;
            int h = 0;
            #pragma unroll
            for (int q = 0; q < 16; ++q) h += s_p[bi][q][v2];
            int b = bblk * 4 + bi, v = vblk * 64 + v2;
            if (!mode1) {
                int sim = 16384 - 2 * h;                  // [-16384, 16384]
                int sh = sim >> 8, sl = sim & 255;        // sim = 256*sh + sl exactly
                u32 val = (u32)(__float_as_uint((float)sh) >> 16)
                        | ((u32)(__float_as_uint((float)sl) >> 16) << 16);
                int mw = b >> 4, brow = b & 15;           // frag-order (verified r10/r11)
                int kc = v >> 5, kgrp = (v >> 3) & 3, j = v & 7;
                int uidx = ((((mw * 8 + kc) * 4 + (j >> 1)) * 64) + kgrp * 16 + brow) * 2 + (j & 1);
                ast32(&simAB[f * 16384 + uidx], val);
            } else {
                ast32(&simAB[((f * 64 + b) << 8) + v], (u32)(16384 - h));   // linear q16
            }
        }
        // ---- barrier (8 per-group counters, monotonic target) ----
        __syncthreads();                                   // drains vmcnt: stores MALL-visible
        if (t == 0) atomicAdd(&bar[(bid & 7) * 8], 1ull);
        ++ph;
        if (t < 8) {
            while (ald(&bar[t * 8]) < (ull)(32 * ph)) __builtin_amdgcn_s_sleep(2);
        }
        __syncthreads();
        if (mode1) break;

        // ================= phase B: est = sign(GEMM) via MFMA (verified r10) =================
        {
            int mw = wave & 3, qtr = wave >> 2;
            const ull* ab8 = (const ull*)simAB + (size_t)f * 8192;
            bf16x8 Ahi[8], Alo[8];
            #pragma unroll
            for (int kc = 0; kc < 8; ++kc) {
                union { u32 u[4]; bf16x8 v; } H, L;
                #pragma unroll
                for (int n = 0; n < 4; ++n) {
                    ull w = ald(ab8 + (((mw * 8 + kc) * 4 + n) * 64) + lane);  // coalesced 512B
                    H.u[n] = (u32)(w & 0xFFFFull) | (((u32)(w >> 32) & 0xFFFFu) << 16);
                    L.u[n] = ((u32)(w >> 16) & 0xFFFFu) | ((u32)(w >> 48) << 16);
                }
                Ahi[kc] = H.v; Alo[kc] = L.v;
            }
            #pragma unroll
            for (int ntl = 0; ntl < 4; ++ntl) {
                int nt = qtr * 4 + ntl;
                f32x4 acch = {0.f, 0.f, 0.f, 0.f}, accl = {0.f, 0.f, 0.f, 0.f};
                #pragma unroll
                for (int kc = 0; kc < 8; ++kc) {
                    ull w = s_bT[(kc >> 1) * 256 + nt * 16 + (lane & 15)];
                    u32 bits = (u32)(w >> ((kc & 1) * 32 + (lane >> 4) * 8)) & 0xFFu;
                    union { u32 u[4]; bf16x8 v; } B;
                    B.u[0] = 0x3F803F80 | ((bits & 1u) << 15)        | ((bits & 2u) << 30);
                    B.u[1] = 0x3F803F80 | (((bits >> 2) & 1u) << 15) | (((bits >> 2) & 2u) << 30);
                    B.u[2] = 0x3F803F80 | (((bits >> 4) & 1u) << 15) | (((bits >> 4) & 2u) << 30);
                    B.u[3] = 0x3F803F80 | (((bits >> 6) & 1u) << 15) | (((bits >> 6) & 2u) << 30);
                    acch = __builtin_amdgcn_mfma_f32_16x16x32_bf16(Ahi[kc], B.v, acch, 0, 0, 0);
                    accl = __builtin_amdgcn_mfma_f32_16x16x32_bf16(Alo[kc], B.v, accl, 0, 0, 0);
                }
                #pragma unroll
                for (int r = 0; r < 4; ++r) {
                    float S = 256.0f * acch[r] + accl[r];   // exact int, |S| < 2^23
                    ull m = __ballot(S < 0.0f);
                    if (lane == 0) s_ball[wave * 4 + ntl][r] = m;
                }
            }
        }
        __syncthreads();
        if (t < 256) {
            int b = t >> 2, w4 = t & 3;
            int wv = (w4 << 2) | (b >> 4);                  // wave with (mw=b>>4, qtr=w4)
            ull word = 0;
            #pragma unroll
            for (int k = 0; k < 4; ++k) {
                ull m = s_ball[wv * 4 + k][b & 3];
                word |= ((m >> (((b >> 2) & 3) * 16)) & 0xFFFFull) << (k * 16);
            }
            ast(&estOut[((size_t)(b * 4 + f)) * 256 + dblk * 4 + w4], word);
        }
        // ---- barrier ----
        __syncthreads();
        if (t == 0) atomicAdd(&bar[(bid & 7) * 8], 1ull);
        ++ph;
        if (t < 8) {
            while (ald(&bar[t * 8]) < (ull)(32 * ph)) __builtin_amdgcn_s_sleep(2);
        }
        __syncthreads();
    }

    // ================= final: argmax|sim| + unpack est (verified r10) =================
    if (t < 64) {
        int b2 = bid >> 2, f2 = bid & 3;
        const ull* sf = (const ull*)(simAB + ((size_t)(f2 * 64 + b2) << 8)) + t * 2;
        ull w0 = ald(sf), w1 = ald(sf + 1);
        int qv[4] = { (int)(u32)w0, (int)(u32)(w0 >> 32),
                      (int)(u32)w1, (int)(u32)(w1 >> 32) };
        int best_a = -1, best_v = 0;
        #pragma unroll
        for (int k = 0; k < 4; ++k) {
            int sim = 2 * qv[k] - 16384;
            int a = sim < 0 ? -sim : sim;
            if (a > best_a) { best_a = a; best_v = t * 4 + k; }   // strict > keeps first index
        }
        #pragma unroll
        for (int off = 1; off < 64; off <<= 1) {
            int oa = __shfl_xor(best_a, off);
            int ov = __shfl_xor(best_v, off);
            if (oa > best_a || (oa == best_a && ov < best_v)) { best_a = oa; best_v = ov; }
        }
        if (t == 0) out[4194304 + b2 * 4 + f2] = (float)best_v;
    }
    {   // unpack est0 -> +-1.0f: block bid covers words bid*256..+256
        ull w = ald(&est0[bid * 256 + (t >> 2)]);
        u32 bits = (u32)(w >> ((t & 3) * 16)) & 0xFFFFu;
        int base = bid * 16384 + (t >> 2) * 64 + (t & 3) * 16;
        #pragma unroll
        for (int j = 0; j < 4; ++j) {
            float4 o;
            o.x = ((bits >> (j * 4 + 0)) & 1u) ? -1.0f : 1.0f;
            o.y = ((bits >> (j * 4 + 1)) & 1u) ? -1.0f : 1.0f;
            o.z = ((bits >> (j * 4 + 2)) & 1u) ? -1.0f : 1.0f;
            o.w = ((bits >> (j * 4 + 3)) & 1u) ? -1.0f : 1.0f;
            *(float4*)(out + base + j * 4) = o;
        }
    }
}

extern "C" void kernel_launch(void* const* d_in, const int* in_sizes, int n_in,
                              void* d_out, int out_size, void* d_ws, size_t ws_size,
                              hipStream_t stream) {
    const float* input    = (const float*)d_in[0];
    const float* init_est = (const float*)d_in[1];
    const float* cb       = (const float*)d_in[2];
    float* out = (float*)d_out;
    char* ws = (char*)d_ws;

    ull* in_bits = (ull*)(ws + 0);
    ull* est0    = (ull*)(ws + 131072);
    ull* est1    = (ull*)(ws + 655360);
    ull* cbw     = (ull*)(ws + 1179648);
    ull* cbT     = (ull*)(ws + 3276800);
    u32* simAB   = (u32*)(ws + 5373952);
    ull* bar     = (ull*)(ws + 5636096);

    pack_mega<<<1344, 1024, 0, stream>>>(input, init_est, cb, in_bits, est0, cbw, bar);
    pack_cbT<<<1024, 1024, 0, stream>>>(cbw, cbT);

    void* kargs[] = {
        (void*)&in_bits, (void*)&est0, (void*)&est1, (void*)&cbw, (void*)&cbT,
        (void*)&simAB, (void*)&bar, (void*)&out
    };
    hipLaunchCooperativeKernel(reinterpret_cast<void*>(reso_kernel),
                               dim3(256, 1, 1), dim3(1024, 1, 1), kargs, 0, stream);
}